// Round 14
// baseline (223.816 us; speedup 1.0000x reference)
//
#include <hip/hip_runtime.h>
#include <hip/hip_fp16.h>
#include <math.h>

#define NN 100000
#define F 64
#define NC 47
#define NSUP 391       // ceil(NN/256) super-bins
#define SUPR 256       // rows per super-bin
#define ACHUNK 4096    // edges per binA_direct block (LDS int2 stash = 32 KB)
#define PAD 5120       // padded bucket capacity per super (mean 4096, sd ~64, +16 sigma)

// ---------------------------------------------------------------------------
// binA_direct: single pass over ei (dtype detected per-block by wave 0's
// ballot). LDS-stash per 4096-edge chunk, LDS histogram by super (dst>>8),
// reserve contiguous segment per (block,super) via one global atomicAdd,
// write payload src|dstLocal<<17 directly. (round-13 proven, byte-identical)
// ---------------------------------------------------------------------------
__global__ __launch_bounds__(256) void binA_direct_kernel(const void* __restrict__ ei,
                                                          int* __restrict__ superCnt,
                                                          unsigned* __restrict__ superArr,
                                                          int E) {
    __shared__ int2 ed[ACHUNK];          // 32 KB
    __shared__ int h[512], gbase[512];
    __shared__ int is64_s;
    int t = threadIdx.x;
    if (t < 64) {
        int v = ((const int*)ei)[2 * t + 1];
        unsigned long long ball = __ballot(v == 0);
        if (t == 0) is64_s = (ball == ~0ULL) ? 1 : 0;   // all-zero odd words => int64
    }
    h[t] = 0; h[t + 256] = 0;
    __syncthreads();
    bool is64 = (is64_s != 0);
    int cb = blockIdx.x * ACHUNK;
    int ce = min(cb + ACHUNK, E);
    for (int i = cb + t; i < ce; i += 256) {
        int s, d;
        if (is64) {
            s = (int)((const long long*)ei)[i];
            d = (int)((const long long*)ei)[(size_t)E + i];
        } else {
            s = ((const int*)ei)[i];
            d = ((const int*)ei)[(size_t)E + i];
        }
        ed[i - cb] = make_int2(s, d);
        atomicAdd(&h[d >> 8], 1);
    }
    __syncthreads();
    for (int b = t; b < 512; b += 256) {
        int c = h[b];
        gbase[b] = (b < NSUP && c > 0) ? atomicAdd(&superCnt[b], c) : 0;
        h[b] = 0;                         // reuse as local cursor
    }
    __syncthreads();
    int nloc = ce - cb;
    for (int i = t; i < nloc; i += 256) {
        int2 e = ed[i];
        int sup = e.y >> 8;
        int pos = atomicAdd(&h[sup], 1);
        unsigned pk = (unsigned)e.x | ((unsigned)(e.y & (SUPR - 1)) << 17);
        superArr[(size_t)sup * PAD + gbase[sup] + pos] = pk;
    }
}

// ---------------------------------------------------------------------------
// superscan: exclusive scan of superCnt (391) -> superBase[0..391].
// ---------------------------------------------------------------------------
__global__ __launch_bounds__(512) void superscan_kernel(const int* __restrict__ superCnt,
                                                        int* __restrict__ superBase) {
    __shared__ int sc[512];
    int t = threadIdx.x;
    int v = (t < NSUP) ? superCnt[t] : 0;
    sc[t] = v;
    __syncthreads();
    for (int off = 1; off < 512; off <<= 1) {
        int a = (t >= off) ? sc[t - off] : 0;
        __syncthreads();
        sc[t] += a;
        __syncthreads();
    }
    if (t < NSUP) superBase[t] = sc[t] - v;
    if (t == NSUP - 1) superBase[NSUP] = sc[t];   // == E
}

// ---------------------------------------------------------------------------
// binB: one 256-thread block per super. LDS histogram of 256 local rows
// (= in-degree), wave-level scan -> rowptr + dinv, rank-and-place into
// esrc, AND (new) block-cooperative f2h prescale of this super's x rows:
// xh[r][:] = fp16(x[r][:] * dinv[r]) — absorbs the old f2h_scale kernel.
// ---------------------------------------------------------------------------
__global__ __launch_bounds__(256) void binB_kernel(const unsigned* __restrict__ superArr,
                                                   const int* __restrict__ superCnt,
                                                   const int* __restrict__ superBase,
                                                   const float4* __restrict__ x4,
                                                   int* __restrict__ rowptr,
                                                   float* __restrict__ dinv,
                                                   unsigned* __restrict__ esrc,
                                                   uint2* __restrict__ xh, int E) {
    __shared__ int hist[256];
    __shared__ int cur[256];
    __shared__ float dloc[256];
    __shared__ int wsum[4], wbase[4];
    int s = blockIdx.x, t = threadIdx.x;
    int wb = superBase[s];
    int cnt = superCnt[s];
    const unsigned* arr = superArr + (size_t)s * PAD;
    hist[t] = 0;
    __syncthreads();
    for (int i = t; i < cnt; i += 256)
        atomicAdd(&hist[(arr[i] >> 17) & (SUPR - 1)], 1);
    __syncthreads();
    int myv = hist[t];
    int lane = t & 63, w = t >> 6;
    int v = myv;
#pragma unroll
    for (int off = 1; off < 64; off <<= 1) {
        int u = __shfl_up(v, off, 64);
        if (lane >= off) v += u;
    }
    if (lane == 63) wsum[w] = v;
    __syncthreads();
    if (t == 0) {
        int r = 0;
#pragma unroll
        for (int j = 0; j < 4; ++j) { wbase[j] = r; r += wsum[j]; }
    }
    __syncthreads();
    int excl = v + wbase[w] - myv;       // exclusive prefix of row t within super
    int gr = s * SUPR + t;
    float dv = (myv > 0) ? rsqrtf((float)myv) : 0.0f;
    if (gr < NN) {
        rowptr[gr] = wb + excl;
        dinv[gr] = dv;
    }
    if (s == NSUP - 1 && t == 0) rowptr[NN] = E;
    cur[t] = excl;
    dloc[t] = dv;
    __syncthreads();
    for (int i = t; i < cnt; i += 256) {
        unsigned e = arr[i];
        int r = (e >> 17) & (SUPR - 1);
        int pos = atomicAdd(&cur[r], 1);
        esrc[wb + pos] = e & 0x1FFFFu;
    }
    // f2h prescale for this super's rows (coalesced, block-cooperative)
    int row0 = s * SUPR;
    int nrow = min(SUPR, NN - row0);
    for (int i = t; i < nrow * 16; i += 256) {
        int rl = i >> 4;
        float d = dloc[rl];
        float4 vv = x4[(size_t)(row0 + rl) * 16 + (i & 15)];
        __half2 h01 = __floats2half2_rn(vv.x * d, vv.y * d);
        __half2 h23 = __floats2half2_rn(vv.z * d, vv.w * d);
        uint2 r;
        r.x = *(const unsigned*)&h01;
        r.y = *(const unsigned*)&h23;
        xh[(size_t)(row0 + rl) * 16 + (i & 15)] = r;
    }
}

// ---------------------------------------------------------------------------
// Shared device helpers
// ---------------------------------------------------------------------------
__device__ __forceinline__ float4 conv_row(const uint2* __restrict__ xh,
                                           const int* __restrict__ rowptr,
                                           const unsigned* __restrict__ esrc,
                                           int row, int lane, int es, int f4) {
    int beg = rowptr[row], end = rowptr[row + 1];
    float4 acc = make_float4(0.f, 0.f, 0.f, 0.f);
    for (int base = beg; base < end; base += 64) {
        int m = end - base;
        if (m > 64) m = 64;
        int pk = (lane < m) ? (int)esrc[base + lane] : 0;
        int iters = (m + 3) >> 2;
        int k = 0;
        for (; k + 4 <= iters; k += 4) {
            int i0 = 4 * k + es, i1 = i0 + 4, i2 = i0 + 8, i3 = i0 + 12;
            int s0 = __shfl(pk, i0, 64);
            int s1 = __shfl(pk, i1, 64);
            int s2 = __shfl(pk, i2, 64);
            int s3 = __shfl(pk, i3, 64);
            float w0 = (i0 < m) ? 1.0f : 0.0f;
            float w1 = (i1 < m) ? 1.0f : 0.0f;
            float w2 = (i2 < m) ? 1.0f : 0.0f;
            float w3 = (i3 < m) ? 1.0f : 0.0f;
            uint2 v0 = xh[(size_t)s0 * 16 + f4];
            uint2 v1 = xh[(size_t)s1 * 16 + f4];
            uint2 v2 = xh[(size_t)s2 * 16 + f4];
            uint2 v3 = xh[(size_t)s3 * 16 + f4];
            float2 a01 = __half22float2(*reinterpret_cast<const __half2*>(&v0.x));
            float2 a23 = __half22float2(*reinterpret_cast<const __half2*>(&v0.y));
            acc.x = fmaf(a01.x, w0, acc.x); acc.y = fmaf(a01.y, w0, acc.y);
            acc.z = fmaf(a23.x, w0, acc.z); acc.w = fmaf(a23.y, w0, acc.w);
            float2 b01 = __half22float2(*reinterpret_cast<const __half2*>(&v1.x));
            float2 b23 = __half22float2(*reinterpret_cast<const __half2*>(&v1.y));
            acc.x = fmaf(b01.x, w1, acc.x); acc.y = fmaf(b01.y, w1, acc.y);
            acc.z = fmaf(b23.x, w1, acc.z); acc.w = fmaf(b23.y, w1, acc.w);
            float2 c01 = __half22float2(*reinterpret_cast<const __half2*>(&v2.x));
            float2 c23 = __half22float2(*reinterpret_cast<const __half2*>(&v2.y));
            acc.x = fmaf(c01.x, w2, acc.x); acc.y = fmaf(c01.y, w2, acc.y);
            acc.z = fmaf(c23.x, w2, acc.z); acc.w = fmaf(c23.y, w2, acc.w);
            float2 d01 = __half22float2(*reinterpret_cast<const __half2*>(&v3.x));
            float2 d23 = __half22float2(*reinterpret_cast<const __half2*>(&v3.y));
            acc.x = fmaf(d01.x, w3, acc.x); acc.y = fmaf(d01.y, w3, acc.y);
            acc.z = fmaf(d23.x, w3, acc.z); acc.w = fmaf(d23.y, w3, acc.w);
        }
        for (; k < iters; ++k) {
            int i0 = 4 * k + es;
            int s0 = __shfl(pk, i0, 64);
            float w0 = (i0 < m) ? 1.0f : 0.0f;
            uint2 v0 = xh[(size_t)s0 * 16 + f4];
            float2 a01 = __half22float2(*reinterpret_cast<const __half2*>(&v0.x));
            float2 a23 = __half22float2(*reinterpret_cast<const __half2*>(&v0.y));
            acc.x = fmaf(a01.x, w0, acc.x); acc.y = fmaf(a01.y, w0, acc.y);
            acc.z = fmaf(a23.x, w0, acc.z); acc.w = fmaf(a23.y, w0, acc.w);
        }
    }
#pragma unroll
    for (int off = 16; off <= 32; off <<= 1) {
        acc.x += __shfl_xor(acc.x, off, 64);
        acc.y += __shfl_xor(acc.y, off, 64);
        acc.z += __shfl_xor(acc.z, off, 64);
        acc.w += __shfl_xor(acc.w, off, 64);
    }
    return acc;   // valid in lanes with es==0
}

// ---------------------------------------------------------------------------
// convlin1: fused conv1 + lin1. Block = 64-row tile. Conv phase: 4 waves x
// 16 rows sequential, stage relu(dinv*acc) as f32 DIRECTLY into the lin LDS
// tile (no bufA round-trip). Lin phase: round-4 proven register-tiled GEMM;
// epilogue emits fp16(relu(.)*dinv[row]) = prescaled conv2 operand.
// ---------------------------------------------------------------------------
__global__ __launch_bounds__(256) void convlin1_kernel(const uint2* __restrict__ xh,
                                                       const int* __restrict__ rowptr,
                                                       const unsigned* __restrict__ esrc,
                                                       const float* __restrict__ dinv,
                                                       const float* __restrict__ W1,
                                                       const float* __restrict__ b1,
                                                       __half* __restrict__ outh, int n) {
    __shared__ float wt[64 * 64];
    __shared__ float ht[64 * 64];
    int t = threadIdx.x;
    for (int i = t; i < 64 * 64; i += 256) {
        int k = i >> 6, c = i & 63;
        int kq = k >> 2, slot = kq ^ (c & 7);
        wt[c * 64 + slot * 4 + (k & 3)] = W1[i];
    }
    int row0 = blockIdx.x * 64;
    int w = t >> 6, lane = t & 63, es = lane >> 4, f4 = lane & 15;
    float4* ht4 = (float4*)ht;
    for (int rr = 0; rr < 16; ++rr) {
        int rl = w * 16 + rr;
        int row = row0 + rl;
        float4 acc = make_float4(0.f, 0.f, 0.f, 0.f);
        if (row < n) acc = conv_row(xh, rowptr, esrc, row, lane, es, f4);
        if (es == 0) {
            float dv = (row < n) ? dinv[row] : 0.0f;
            float4 o;
            o.x = fmaxf(acc.x * dv, 0.f); o.y = fmaxf(acc.y * dv, 0.f);
            o.z = fmaxf(acc.z * dv, 0.f); o.w = fmaxf(acc.w * dv, 0.f);
            ht4[rl * 16 + (f4 ^ ((rl >> 2) & 7))] = o;
        }
    }
    __syncthreads();
    const float4* wt4 = (const float4*)wt;
    const float4* ht4c = (const float4*)ht;

    int tx = t & 15, ty = t >> 4;
    float acc[4][4] = {};
#pragma unroll 2
    for (int kq = 0; kq < 16; ++kq) {
        int wslot = kq ^ (tx & 7);
        float4 b0 = wt4[(tx +  0) * 16 + wslot];
        float4 b1v = wt4[(tx + 16) * 16 + wslot];
        float4 b2v = wt4[(tx + 32) * 16 + wslot];
        float4 b3v = wt4[(tx + 48) * 16 + wslot];
        int aslot = kq ^ (ty & 7);
#pragma unroll
        for (int i = 0; i < 4; ++i) {
            float4 a = ht4c[(4 * ty + i) * 16 + aslot];
            acc[i][0] = fmaf(a.x, b0.x,  fmaf(a.y, b0.y,  fmaf(a.z, b0.z,  fmaf(a.w, b0.w,  acc[i][0]))));
            acc[i][1] = fmaf(a.x, b1v.x, fmaf(a.y, b1v.y, fmaf(a.z, b1v.z, fmaf(a.w, b1v.w, acc[i][1]))));
            acc[i][2] = fmaf(a.x, b2v.x, fmaf(a.y, b2v.y, fmaf(a.z, b2v.z, fmaf(a.w, b2v.w, acc[i][2]))));
            acc[i][3] = fmaf(a.x, b3v.x, fmaf(a.y, b3v.y, fmaf(a.z, b3v.z, fmaf(a.w, b3v.w, acc[i][3]))));
        }
    }
    float bj[4];
#pragma unroll
    for (int g = 0; g < 4; ++g) bj[g] = b1[tx + 16 * g];
    int r0 = row0 + 4 * ty;
#pragma unroll
    for (int i = 0; i < 4; ++i) {
        int r = r0 + i;
        if (r >= n) break;
        float dv = dinv[r];
#pragma unroll
        for (int g = 0; g < 4; ++g)
            outh[(size_t)r * 64 + tx + 16 * g] =
                __float2half(fmaxf(acc[i][g] + bj[g], 0.0f) * dv);
    }
}

// ---------------------------------------------------------------------------
// convlin2: fused conv2 + lin2 + log_softmax. Same structure; gathers the
// prescaled fp16 lin1 output, stages relu(dinv*acc), lin2 + log_softmax.
// ---------------------------------------------------------------------------
__global__ __launch_bounds__(256) void convlin2_kernel(const uint2* __restrict__ hh,
                                                       const int* __restrict__ rowptr,
                                                       const unsigned* __restrict__ esrc,
                                                       const float* __restrict__ dinv,
                                                       const float* __restrict__ W2,
                                                       const float* __restrict__ b2,
                                                       float* __restrict__ out, int n) {
    __shared__ float wt[64 * 64];   // cols >= 47 zero-padded
    __shared__ float ht[64 * 64];
    int t = threadIdx.x;
    for (int i = t; i < 64 * 64; i += 256) {
        int k = i >> 6, c = i & 63;
        int kq = k >> 2, slot = kq ^ (c & 7);
        wt[c * 64 + slot * 4 + (k & 3)] = (c < NC) ? W2[k * NC + c] : 0.0f;
    }
    int row0 = blockIdx.x * 64;
    int w = t >> 6, lane = t & 63, es = lane >> 4, f4 = lane & 15;
    float4* ht4 = (float4*)ht;
    for (int rr = 0; rr < 16; ++rr) {
        int rl = w * 16 + rr;
        int row = row0 + rl;
        float4 acc = make_float4(0.f, 0.f, 0.f, 0.f);
        if (row < n) acc = conv_row(hh, rowptr, esrc, row, lane, es, f4);
        if (es == 0) {
            float dv = (row < n) ? dinv[row] : 0.0f;
            float4 o;
            o.x = fmaxf(acc.x * dv, 0.f); o.y = fmaxf(acc.y * dv, 0.f);
            o.z = fmaxf(acc.z * dv, 0.f); o.w = fmaxf(acc.w * dv, 0.f);
            ht4[rl * 16 + (f4 ^ ((rl >> 2) & 7))] = o;
        }
    }
    __syncthreads();
    const float4* wt4 = (const float4*)wt;
    const float4* ht4c = (const float4*)ht;

    int tx = t & 15, ty = t >> 4;
    float acc[4][4] = {};
#pragma unroll 2
    for (int kq = 0; kq < 16; ++kq) {
        int wslot = kq ^ (tx & 7);
        float4 b0 = wt4[(tx +  0) * 16 + wslot];
        float4 b1v = wt4[(tx + 16) * 16 + wslot];
        float4 b2v = wt4[(tx + 32) * 16 + wslot];
        float4 b3v = wt4[(tx + 48) * 16 + wslot];
        int aslot = kq ^ (ty & 7);
#pragma unroll
        for (int i = 0; i < 4; ++i) {
            float4 a = ht4c[(4 * ty + i) * 16 + aslot];
            acc[i][0] = fmaf(a.x, b0.x,  fmaf(a.y, b0.y,  fmaf(a.z, b0.z,  fmaf(a.w, b0.w,  acc[i][0]))));
            acc[i][1] = fmaf(a.x, b1v.x, fmaf(a.y, b1v.y, fmaf(a.z, b1v.z, fmaf(a.w, b1v.w, acc[i][1]))));
            acc[i][2] = fmaf(a.x, b2v.x, fmaf(a.y, b2v.y, fmaf(a.z, b2v.z, fmaf(a.w, b2v.w, acc[i][2]))));
            acc[i][3] = fmaf(a.x, b3v.x, fmaf(a.y, b3v.y, fmaf(a.z, b3v.z, fmaf(a.w, b3v.w, acc[i][3]))));
        }
    }
    bool vm[4];
    float bj[4];
#pragma unroll
    for (int g = 0; g < 4; ++g) {
        int c = tx + 16 * g;
        vm[g] = (c < NC);
        bj[g] = vm[g] ? b2[c] : 0.0f;
    }
    int r0 = row0 + 4 * ty;
#pragma unroll
    for (int i = 0; i < 4; ++i) {
        int r = r0 + i;
        float v[4];
        float m = -INFINITY;
#pragma unroll
        for (int g = 0; g < 4; ++g) {
            v[g] = acc[i][g] + bj[g];
            if (vm[g]) m = fmaxf(m, v[g]);
        }
#pragma unroll
        for (int off = 8; off > 0; off >>= 1) m = fmaxf(m, __shfl_xor(m, off, 64));
        float s = 0.0f;
#pragma unroll
        for (int g = 0; g < 4; ++g)
            if (vm[g]) s += expf(v[g] - m);
#pragma unroll
        for (int off = 8; off > 0; off >>= 1) s += __shfl_xor(s, off, 64);
        float lse = m + logf(s);
        if (r < n) {
#pragma unroll
            for (int g = 0; g < 4; ++g)
                if (vm[g]) out[(size_t)r * NC + tx + 16 * g] = v[g] - lse;
        }
    }
}

// ---------------------------------------------------------------------------
extern "C" void kernel_launch(void* const* d_in, const int* in_sizes, int n_in,
                              void* d_out, int out_size, void* d_ws, size_t ws_size,
                              hipStream_t stream) {
    const float* x  = (const float*)d_in[0];
    const void*  ei = d_in[1];
    const float* W1 = (const float*)d_in[2];
    const float* b1 = (const float*)d_in[3];
    const float* W2 = (const float*)d_in[4];
    const float* b2 = (const float*)d_in[5];
    float* out = (float*)d_out;

    const int E = in_sizes[1] / 2;

    // workspace carve-out (256B aligned)
    char* ws = (char*)d_ws;
    size_t off = 0;
    auto alloc = [&](size_t bytes) -> void* {
        void* p = ws + off;
        off = (off + bytes + 255) & ~(size_t)255;
        return p;
    };
    float*    dinv      = (float*)   alloc((size_t)NN * 4);
    int*      superCnt  = (int*)     alloc(512 * 4);
    int*      superBase = (int*)     alloc(512 * 4);
    unsigned* superArr  = (unsigned*)alloc((size_t)NSUP * PAD * 4);   // 8.0 MB padded
    int*      rowptr    = (int*)     alloc((size_t)(NN + 1) * 4);
    unsigned* esrc      = (unsigned*)alloc((size_t)E * 4);            // 4 B payload
    uint2*    xh        = (uint2*)   alloc((size_t)NN * 16 * 8);      // fp16 xs
    __half*   bufBh     = (__half*)  alloc((size_t)NN * F * 2);       // fp16 lin1 out

    hipMemsetAsync(superCnt, 0, 512 * 4, stream);

    binA_direct_kernel<<<(E + ACHUNK - 1) / ACHUNK, 256, 0, stream>>>(
        ei, superCnt, superArr, E);
    superscan_kernel<<<1, 512, 0, stream>>>(superCnt, superBase);
    binB_kernel<<<NSUP, 256, 0, stream>>>(
        superArr, superCnt, superBase, (const float4*)x, rowptr, dinv, esrc, xh, E);

    const int lin_blocks = (NN + 63) / 64;    // 1563

    // conv1 + lin1 fused: xs -> (LDS) -> bufBh (fp16, prescaled)
    convlin1_kernel<<<lin_blocks, 256, 0, stream>>>(xh, rowptr, esrc, dinv,
                                                    W1, b1, bufBh, NN);

    // conv2 + lin2 + log_softmax fused: bufBh -> (LDS) -> out
    convlin2_kernel<<<lin_blocks, 256, 0, stream>>>((const uint2*)bufBh, rowptr, esrc,
                                                    dinv, W2, b2, out, NN);
}

// Round 16
// 177.207 us; speedup vs baseline: 1.2630x; 1.2630x over previous
//
#include <hip/hip_runtime.h>
#include <hip/hip_fp16.h>
#include <math.h>

#define NN 100000
#define F 64
#define NC 47
#define NSUP 391       // ceil(NN/256) super-bins
#define SUPR 256       // rows per super-bin
#define ACHUNK 4096    // edges per binA_direct block (LDS int2 stash = 32 KB)
#define PAD 5120       // padded bucket capacity per super (mean 4096, sd ~64, +16 sigma)

// ---------------------------------------------------------------------------
// binA_direct: single pass over ei (dtype detected per-block by wave 0's
// ballot). LDS-stash per 4096-edge chunk, LDS histogram by super (dst>>8),
// reserve contiguous segment per (block,super) via one global atomicAdd,
// write payload src|dstLocal<<17 directly. (round-13 proven, byte-identical)
// ---------------------------------------------------------------------------
__global__ __launch_bounds__(256) void binA_direct_kernel(const void* __restrict__ ei,
                                                          int* __restrict__ superCnt,
                                                          unsigned* __restrict__ superArr,
                                                          int E) {
    __shared__ int2 ed[ACHUNK];          // 32 KB
    __shared__ int h[512], gbase[512];
    __shared__ int is64_s;
    int t = threadIdx.x;
    if (t < 64) {
        int v = ((const int*)ei)[2 * t + 1];
        unsigned long long ball = __ballot(v == 0);
        if (t == 0) is64_s = (ball == ~0ULL) ? 1 : 0;   // all-zero odd words => int64
    }
    h[t] = 0; h[t + 256] = 0;
    __syncthreads();
    bool is64 = (is64_s != 0);
    int cb = blockIdx.x * ACHUNK;
    int ce = min(cb + ACHUNK, E);
    for (int i = cb + t; i < ce; i += 256) {
        int s, d;
        if (is64) {
            s = (int)((const long long*)ei)[i];
            d = (int)((const long long*)ei)[(size_t)E + i];
        } else {
            s = ((const int*)ei)[i];
            d = ((const int*)ei)[(size_t)E + i];
        }
        ed[i - cb] = make_int2(s, d);
        atomicAdd(&h[d >> 8], 1);
    }
    __syncthreads();
    for (int b = t; b < 512; b += 256) {
        int c = h[b];
        gbase[b] = (b < NSUP && c > 0) ? atomicAdd(&superCnt[b], c) : 0;
        h[b] = 0;                         // reuse as local cursor
    }
    __syncthreads();
    int nloc = ce - cb;
    for (int i = t; i < nloc; i += 256) {
        int2 e = ed[i];
        int sup = e.y >> 8;
        int pos = atomicAdd(&h[sup], 1);
        unsigned pk = (unsigned)e.x | ((unsigned)(e.y & (SUPR - 1)) << 17);
        superArr[(size_t)sup * PAD + gbase[sup] + pos] = pk;
    }
}

// ---------------------------------------------------------------------------
// superscan: exclusive scan of superCnt (391) -> superBase[0..391].
// ---------------------------------------------------------------------------
__global__ __launch_bounds__(512) void superscan_kernel(const int* __restrict__ superCnt,
                                                        int* __restrict__ superBase) {
    __shared__ int sc[512];
    int t = threadIdx.x;
    int v = (t < NSUP) ? superCnt[t] : 0;
    sc[t] = v;
    __syncthreads();
    for (int off = 1; off < 512; off <<= 1) {
        int a = (t >= off) ? sc[t - off] : 0;
        __syncthreads();
        sc[t] += a;
        __syncthreads();
    }
    if (t < NSUP) superBase[t] = sc[t] - v;
    if (t == NSUP - 1) superBase[NSUP] = sc[t];   // == E
}

// ---------------------------------------------------------------------------
// binB: one 256-thread block per super. LDS histogram of 256 local rows
// (= in-degree), wave-level scan -> rowptr + dinv, rank-and-place into
// esrc, plus block-cooperative f2h prescale of this super's x rows:
// xh[r][:] = fp16(x[r][:] * dinv[r]). (round-13 proven, byte-identical)
// ---------------------------------------------------------------------------
__global__ __launch_bounds__(256) void binB_kernel(const unsigned* __restrict__ superArr,
                                                   const int* __restrict__ superCnt,
                                                   const int* __restrict__ superBase,
                                                   const float4* __restrict__ x4,
                                                   int* __restrict__ rowptr,
                                                   float* __restrict__ dinv,
                                                   unsigned* __restrict__ esrc,
                                                   uint2* __restrict__ xh, int E) {
    __shared__ int hist[256];
    __shared__ int cur[256];
    __shared__ float dloc[256];
    __shared__ int wsum[4], wbase[4];
    int s = blockIdx.x, t = threadIdx.x;
    int wb = superBase[s];
    int cnt = superCnt[s];
    const unsigned* arr = superArr + (size_t)s * PAD;
    hist[t] = 0;
    __syncthreads();
    for (int i = t; i < cnt; i += 256)
        atomicAdd(&hist[(arr[i] >> 17) & (SUPR - 1)], 1);
    __syncthreads();
    int myv = hist[t];
    int lane = t & 63, w = t >> 6;
    int v = myv;
#pragma unroll
    for (int off = 1; off < 64; off <<= 1) {
        int u = __shfl_up(v, off, 64);
        if (lane >= off) v += u;
    }
    if (lane == 63) wsum[w] = v;
    __syncthreads();
    if (t == 0) {
        int r = 0;
#pragma unroll
        for (int j = 0; j < 4; ++j) { wbase[j] = r; r += wsum[j]; }
    }
    __syncthreads();
    int excl = v + wbase[w] - myv;       // exclusive prefix of row t within super
    int gr = s * SUPR + t;
    float dv = (myv > 0) ? rsqrtf((float)myv) : 0.0f;
    if (gr < NN) {
        rowptr[gr] = wb + excl;
        dinv[gr] = dv;
    }
    if (s == NSUP - 1 && t == 0) rowptr[NN] = E;
    cur[t] = excl;
    dloc[t] = dv;
    __syncthreads();
    for (int i = t; i < cnt; i += 256) {
        unsigned e = arr[i];
        int r = (e >> 17) & (SUPR - 1);
        int pos = atomicAdd(&cur[r], 1);
        esrc[wb + pos] = e & 0x1FFFFu;
    }
    // f2h prescale for this super's rows (coalesced, block-cooperative)
    int row0 = s * SUPR;
    int nrow = min(SUPR, NN - row0);
    for (int i = t; i < nrow * 16; i += 256) {
        int rl = i >> 4;
        float d = dloc[rl];
        float4 vv = x4[(size_t)(row0 + rl) * 16 + (i & 15)];
        __half2 h01 = __floats2half2_rn(vv.x * d, vv.y * d);
        __half2 h23 = __floats2half2_rn(vv.z * d, vv.w * d);
        uint2 r;
        r.x = *(const unsigned*)&h01;
        r.y = *(const unsigned*)&h23;
        xh[(size_t)(row0 + rl) * 16 + (i & 15)] = r;
    }
}

// ---------------------------------------------------------------------------
// conv: wave per row, 8 edge-slots x 8 uint4-slices (16 B/lane). Per
// 64-edge batch each lane issues 8 gathers + 8 shfl (was 16+16) — VMEM
// instruction count halves; coalescing unchanged (8 lanes x 16 B = 128 B
// row); FMA count unchanged; reduction = shfl_xor over es bits (8,16,32).
// out[row] = fp16(dinv[row] * sum_e xs[src_e]).
// ---------------------------------------------------------------------------
__device__ __forceinline__ void acc8(const uint4& v, float wgt,
                                     float* accA, float* accB) {
    float2 q0 = __half22float2(*reinterpret_cast<const __half2*>(&v.x));
    float2 q1 = __half22float2(*reinterpret_cast<const __half2*>(&v.y));
    float2 q2 = __half22float2(*reinterpret_cast<const __half2*>(&v.z));
    float2 q3 = __half22float2(*reinterpret_cast<const __half2*>(&v.w));
    accA[0] = fmaf(q0.x, wgt, accA[0]); accA[1] = fmaf(q0.y, wgt, accA[1]);
    accA[2] = fmaf(q1.x, wgt, accA[2]); accA[3] = fmaf(q1.y, wgt, accA[3]);
    accB[0] = fmaf(q2.x, wgt, accB[0]); accB[1] = fmaf(q2.y, wgt, accB[1]);
    accB[2] = fmaf(q3.x, wgt, accB[2]); accB[3] = fmaf(q3.y, wgt, accB[3]);
}

__global__ __launch_bounds__(256) void conv_ps_kernel(const uint4* __restrict__ xh,
                                                      const int* __restrict__ rowptr,
                                                      const unsigned* __restrict__ esrc,
                                                      const float* __restrict__ dinv,
                                                      uint4* __restrict__ outh, int n) {
    int row = blockIdx.x * 4 + (threadIdx.x >> 6);
    if (row >= n) return;
    int lane = threadIdx.x & 63;
    int es = lane >> 3, f4 = lane & 7;
    int beg = rowptr[row], end = rowptr[row + 1];
    float accA[4] = {0.f, 0.f, 0.f, 0.f};
    float accB[4] = {0.f, 0.f, 0.f, 0.f};
    for (int base = beg; base < end; base += 64) {
        int m = end - base;
        if (m > 64) m = 64;
        int pk = (lane < m) ? (int)esrc[base + lane] : 0;
        int iters = (m + 7) >> 3;
        int k = 0;
        for (; k + 2 <= iters; k += 2) {
            int i0 = 8 * k + es, i1 = i0 + 8;
            int s0 = __shfl(pk, i0, 64);
            int s1 = __shfl(pk, i1, 64);
            float w0 = (i0 < m) ? 1.0f : 0.0f;
            float w1 = (i1 < m) ? 1.0f : 0.0f;
            uint4 v0 = xh[(size_t)s0 * 8 + f4];
            uint4 v1 = xh[(size_t)s1 * 8 + f4];
            acc8(v0, w0, accA, accB);
            acc8(v1, w1, accA, accB);
        }
        if (k < iters) {
            int i0 = 8 * k + es;
            int s0 = __shfl(pk, i0, 64);
            float w0 = (i0 < m) ? 1.0f : 0.0f;
            uint4 v0 = xh[(size_t)s0 * 8 + f4];
            acc8(v0, w0, accA, accB);
        }
    }
#pragma unroll
    for (int off = 8; off <= 32; off <<= 1) {
#pragma unroll
        for (int j = 0; j < 4; ++j) {
            accA[j] += __shfl_xor(accA[j], off, 64);
            accB[j] += __shfl_xor(accB[j], off, 64);
        }
    }
    if (es == 0) {
        float dv = dinv[row];
        __half2 h0 = __floats2half2_rn(accA[0] * dv, accA[1] * dv);
        __half2 h1 = __floats2half2_rn(accA[2] * dv, accA[3] * dv);
        __half2 h2 = __floats2half2_rn(accB[0] * dv, accB[1] * dv);
        __half2 h3 = __floats2half2_rn(accB[2] * dv, accB[3] * dv);
        uint4 r;
        r.x = *(const unsigned*)&h0;
        r.y = *(const unsigned*)&h1;
        r.z = *(const unsigned*)&h2;
        r.w = *(const unsigned*)&h3;
        outh[(size_t)row * 8 + f4] = r;
    }
}

// ---------------------------------------------------------------------------
// Register-tiled lin kernels (round-13 proven, byte-identical).
// ---------------------------------------------------------------------------
__device__ __forceinline__ float4 h4_to_f4_relu(uint2 hv) {
    float2 a01 = __half22float2(*reinterpret_cast<const __half2*>(&hv.x));
    float2 a23 = __half22float2(*reinterpret_cast<const __half2*>(&hv.y));
    return make_float4(fmaxf(a01.x, 0.f), fmaxf(a01.y, 0.f),
                       fmaxf(a23.x, 0.f), fmaxf(a23.y, 0.f));
}

__global__ __launch_bounds__(256) void lin1_kernel(const uint2* __restrict__ h2,
                                                   const float* __restrict__ W1,
                                                   const float* __restrict__ b1,
                                                   const float* __restrict__ dinv,
                                                   __half* __restrict__ outh, int n) {
    __shared__ float wt[64 * 64];
    __shared__ float ht[64 * 64];
    int t = threadIdx.x;
    for (int i = t; i < 64 * 64; i += 256) {
        int k = i >> 6, c = i & 63;
        int kq = k >> 2, slot = kq ^ (c & 7);
        wt[c * 64 + slot * 4 + (k & 3)] = W1[i];
    }
    int row0 = blockIdx.x * 64;
    float4* ht4 = (float4*)ht;
#pragma unroll
    for (int j = 0; j < 4; ++j) {
        int flat = t + 256 * j;
        int r = flat >> 4;
        int kq = flat & 15;
        int gr = row0 + r;
        float4 v = (gr < n) ? h4_to_f4_relu(h2[(size_t)gr * 16 + kq])
                            : make_float4(0.f, 0.f, 0.f, 0.f);
        ht4[r * 16 + (kq ^ ((r >> 2) & 7))] = v;
    }
    __syncthreads();
    const float4* wt4 = (const float4*)wt;
    const float4* ht4c = (const float4*)ht;

    int tx = t & 15, ty = t >> 4;
    float acc[4][4] = {};
#pragma unroll 2
    for (int kq = 0; kq < 16; ++kq) {
        int wslot = kq ^ (tx & 7);
        float4 b0 = wt4[(tx +  0) * 16 + wslot];
        float4 b1v = wt4[(tx + 16) * 16 + wslot];
        float4 b2v = wt4[(tx + 32) * 16 + wslot];
        float4 b3v = wt4[(tx + 48) * 16 + wslot];
        int aslot = kq ^ (ty & 7);
#pragma unroll
        for (int i = 0; i < 4; ++i) {
            float4 a = ht4c[(4 * ty + i) * 16 + aslot];
            acc[i][0] = fmaf(a.x, b0.x,  fmaf(a.y, b0.y,  fmaf(a.z, b0.z,  fmaf(a.w, b0.w,  acc[i][0]))));
            acc[i][1] = fmaf(a.x, b1v.x, fmaf(a.y, b1v.y, fmaf(a.z, b1v.z, fmaf(a.w, b1v.w, acc[i][1]))));
            acc[i][2] = fmaf(a.x, b2v.x, fmaf(a.y, b2v.y, fmaf(a.z, b2v.z, fmaf(a.w, b2v.w, acc[i][2]))));
            acc[i][3] = fmaf(a.x, b3v.x, fmaf(a.y, b3v.y, fmaf(a.z, b3v.z, fmaf(a.w, b3v.w, acc[i][3]))));
        }
    }
    float bj[4];
#pragma unroll
    for (int g = 0; g < 4; ++g) bj[g] = b1[tx + 16 * g];
    int r0 = row0 + 4 * ty;
#pragma unroll
    for (int i = 0; i < 4; ++i) {
        int r = r0 + i;
        if (r >= n) break;
        float dv = dinv[r];
#pragma unroll
        for (int g = 0; g < 4; ++g)
            outh[(size_t)r * 64 + tx + 16 * g] =
                __float2half(fmaxf(acc[i][g] + bj[g], 0.0f) * dv);
    }
}

__global__ __launch_bounds__(256) void lin2_kernel(const uint2* __restrict__ h2,
                                                   const float* __restrict__ W2,
                                                   const float* __restrict__ b2,
                                                   float* __restrict__ out, int n) {
    __shared__ float wt[64 * 64];   // cols >= 47 zero-padded
    __shared__ float ht[64 * 64];
    int t = threadIdx.x;
    for (int i = t; i < 64 * 64; i += 256) {
        int k = i >> 6, c = i & 63;
        int kq = k >> 2, slot = kq ^ (c & 7);
        wt[c * 64 + slot * 4 + (k & 3)] = (c < NC) ? W2[k * NC + c] : 0.0f;
    }
    int row0 = blockIdx.x * 64;
    float4* ht4 = (float4*)ht;
#pragma unroll
    for (int j = 0; j < 4; ++j) {
        int flat = t + 256 * j;
        int r = flat >> 4;
        int kq = flat & 15;
        int gr = row0 + r;
        float4 v = (gr < n) ? h4_to_f4_relu(h2[(size_t)gr * 16 + kq])
                            : make_float4(0.f, 0.f, 0.f, 0.f);
        ht4[r * 16 + (kq ^ ((r >> 2) & 7))] = v;
    }
    __syncthreads();
    const float4* wt4 = (const float4*)wt;
    const float4* ht4c = (const float4*)ht;

    int tx = t & 15, ty = t >> 4;
    float acc[4][4] = {};
#pragma unroll 2
    for (int kq = 0; kq < 16; ++kq) {
        int wslot = kq ^ (tx & 7);
        float4 b0 = wt4[(tx +  0) * 16 + wslot];
        float4 b1v = wt4[(tx + 16) * 16 + wslot];
        float4 b2v = wt4[(tx + 32) * 16 + wslot];
        float4 b3v = wt4[(tx + 48) * 16 + wslot];
        int aslot = kq ^ (ty & 7);
#pragma unroll
        for (int i = 0; i < 4; ++i) {
            float4 a = ht4c[(4 * ty + i) * 16 + aslot];
            acc[i][0] = fmaf(a.x, b0.x,  fmaf(a.y, b0.y,  fmaf(a.z, b0.z,  fmaf(a.w, b0.w,  acc[i][0]))));
            acc[i][1] = fmaf(a.x, b1v.x, fmaf(a.y, b1v.y, fmaf(a.z, b1v.z, fmaf(a.w, b1v.w, acc[i][1]))));
            acc[i][2] = fmaf(a.x, b2v.x, fmaf(a.y, b2v.y, fmaf(a.z, b2v.z, fmaf(a.w, b2v.w, acc[i][2]))));
            acc[i][3] = fmaf(a.x, b3v.x, fmaf(a.y, b3v.y, fmaf(a.z, b3v.z, fmaf(a.w, b3v.w, acc[i][3]))));
        }
    }
    bool vm[4];
    float bj[4];
#pragma unroll
    for (int g = 0; g < 4; ++g) {
        int c = tx + 16 * g;
        vm[g] = (c < NC);
        bj[g] = vm[g] ? b2[c] : 0.0f;
    }
    int r0 = row0 + 4 * ty;
#pragma unroll
    for (int i = 0; i < 4; ++i) {
        int r = r0 + i;
        float v[4];
        float m = -INFINITY;
#pragma unroll
        for (int g = 0; g < 4; ++g) {
            v[g] = acc[i][g] + bj[g];
            if (vm[g]) m = fmaxf(m, v[g]);
        }
#pragma unroll
        for (int off = 8; off > 0; off >>= 1) m = fmaxf(m, __shfl_xor(m, off, 64));
        float s = 0.0f;
#pragma unroll
        for (int g = 0; g < 4; ++g)
            if (vm[g]) s += expf(v[g] - m);
#pragma unroll
        for (int off = 8; off > 0; off >>= 1) s += __shfl_xor(s, off, 64);
        float lse = m + logf(s);
        if (r < n) {
#pragma unroll
            for (int g = 0; g < 4; ++g)
                if (vm[g]) out[(size_t)r * NC + tx + 16 * g] = v[g] - lse;
        }
    }
}

// ---------------------------------------------------------------------------
extern "C" void kernel_launch(void* const* d_in, const int* in_sizes, int n_in,
                              void* d_out, int out_size, void* d_ws, size_t ws_size,
                              hipStream_t stream) {
    const float* x  = (const float*)d_in[0];
    const void*  ei = d_in[1];
    const float* W1 = (const float*)d_in[2];
    const float* b1 = (const float*)d_in[3];
    const float* W2 = (const float*)d_in[4];
    const float* b2 = (const float*)d_in[5];
    float* out = (float*)d_out;

    const int E = in_sizes[1] / 2;

    // workspace carve-out (256B aligned)
    char* ws = (char*)d_ws;
    size_t off = 0;
    auto alloc = [&](size_t bytes) -> void* {
        void* p = ws + off;
        off = (off + bytes + 255) & ~(size_t)255;
        return p;
    };
    float*    dinv      = (float*)   alloc((size_t)NN * 4);
    int*      superCnt  = (int*)     alloc(512 * 4);
    int*      superBase = (int*)     alloc(512 * 4);
    unsigned* superArr  = (unsigned*)alloc((size_t)NSUP * PAD * 4);   // 8.0 MB padded
    int*      rowptr    = (int*)     alloc((size_t)(NN + 1) * 4);
    unsigned* esrc      = (unsigned*)alloc((size_t)E * 4);            // 4 B payload
    uint2*    xh        = (uint2*)   alloc((size_t)NN * 16 * 8);      // fp16 xs
    __half*   bufAh     = (__half*)  alloc((size_t)NN * F * 2);       // fp16 conv out
    __half*   bufBh     = (__half*)  alloc((size_t)NN * F * 2);       // fp16 lin1 out

    (void)hipMemsetAsync(superCnt, 0, 512 * 4, stream);

    binA_direct_kernel<<<(E + ACHUNK - 1) / ACHUNK, 256, 0, stream>>>(
        ei, superCnt, superArr, E);
    superscan_kernel<<<1, 512, 0, stream>>>(superCnt, superBase);
    binB_kernel<<<NSUP, 256, 0, stream>>>(
        superArr, superCnt, superBase, (const float4*)x, rowptr, dinv, esrc, xh, E);

    const int conv_blocks = (NN + 3) / 4;     // wave per row, 4 waves/block
    const int lin_blocks = (NN + 63) / 64;    // 1563

    // conv1: xs -> bufAh (true conv1 output, fp16)
    conv_ps_kernel<<<conv_blocks, 256, 0, stream>>>((const uint4*)xh, rowptr, esrc,
                                                    dinv, (uint4*)bufAh, NN);

    // lin1: relu(bufAh) @ W1 + b1, relu, * dinv -> bufBh (fp16, prescaled)
    lin1_kernel<<<lin_blocks, 256, 0, stream>>>((const uint2*)bufAh, W1, b1, dinv,
                                                bufBh, NN);

    // conv2: bufBh -> bufAh (true conv2 output, fp16)
    conv_ps_kernel<<<conv_blocks, 256, 0, stream>>>((const uint4*)bufBh, rowptr, esrc,
                                                    dinv, (uint4*)bufAh, NN);

    // lin2 + log_softmax
    lin2_kernel<<<lin_blocks, 256, 0, stream>>>((const uint2*)bufAh, W2, b2, out, NN);
}